// Round 14
// baseline (385.772 us; speedup 1.0000x reference)
//
#include <hip/hip_runtime.h>
#include <hip/hip_fp16.h>
#include <stdint.h>

#define NN 100000
#define NE 1250000
#define DD 64
#define NL 4

#define NPART3 64            // partitions; one WG owns one partition in fillD
#define PSIZE3 1563          // nodes per partition (64*1563 = 100032 >= NN)
#define TILE4 1024           // int4s per radix tile = 4096 edges
#define NTB ((NE / 4 + TILE4 - 1) / TILE4)        // 306 tiles
#define SCANA_N (NPART3 * NTB)                    // 19584
#define SRCBITS 17           // src < 100000 < 2^17; dlocal < 1563 < 2^11

#define MB2 64               // nodes per fused block
#define L2BLOCKS ((NN + MB2 - 1) / MB2)   // 1563
#define APAD 136             // halfs per A/Bt LDS row
#define CPADH 72             // halfs per C row
#define CPADF 68             // floats per C row

typedef _Float16 half8 __attribute__((ext_vector_type(8)));
typedef _Float16 half2v __attribute__((ext_vector_type(2)));
typedef float floatx4 __attribute__((ext_vector_type(4)));
typedef int intx4 __attribute__((ext_vector_type(4)));

__device__ __forceinline__ unsigned f2h2(float a, float b) {
    __half2 h = __floats2half2_rn(a, b);
    return *reinterpret_cast<unsigned*>(&h);
}
// packed fp16 max on raw bits (maps to v_pk_max_f16)
__device__ __forceinline__ unsigned umax2(unsigned a, unsigned b) {
    half2v x = *reinterpret_cast<half2v*>(&a);
    half2v y = *reinterpret_cast<half2v*>(&b);
    half2v r = __builtin_elementwise_max(x, y);
    return *reinterpret_cast<unsigned*>(&r);
}

// ---- x (fp32) -> hh (fp16) ----
__global__ __launch_bounds__(256) void cast_kernel(const float* __restrict__ x,
                                                   __half* __restrict__ hh) {
    int i = blockIdx.x * 256 + threadIdx.x;
    float4 v = ((const float4*)x)[i];
    uint2 u;
    u.x = f2h2(v.x, v.y);
    u.y = f2h2(v.z, v.w);
    ((uint2*)hh)[i] = u;
}

// ---------------- radix bucketing: edges -> 64 dst-partition buckets ----------------
__global__ __launch_bounds__(256) void countA_kernel(const int* __restrict__ dst,
                                                     int* __restrict__ blockcnt) {
    __shared__ int cnt[NPART3];
    int tid = threadIdx.x;
    if (tid < NPART3) cnt[tid] = 0;
    __syncthreads();
    int b = blockIdx.x;
    #pragma unroll
    for (int r = 0; r < 4; ++r) {
        int i4 = b * TILE4 + r * 256 + tid;
        if (i4 < NE / 4) {
            intx4 d = __builtin_nontemporal_load(&((const intx4*)dst)[i4]);
            atomicAdd(&cnt[(unsigned)d.x / PSIZE3], 1);
            atomicAdd(&cnt[(unsigned)d.y / PSIZE3], 1);
            atomicAdd(&cnt[(unsigned)d.z / PSIZE3], 1);
            atomicAdd(&cnt[(unsigned)d.w / PSIZE3], 1);
        }
    }
    __syncthreads();
    if (tid < NPART3) blockcnt[tid * NTB + b] = cnt[tid];
}

// exclusive scan over NPART3*NTB = 19584 counts (bucket-major -> global offsets)
__global__ __launch_bounds__(1024) void scanA_kernel(int* __restrict__ blockcnt) {
    __shared__ int sm[1024];
    int tid = threadIdx.x;
    int base = tid * 20;
    int e[20];
    int s = 0;
    #pragma unroll
    for (int j = 0; j < 20; ++j) {
        e[j] = (base + j < SCANA_N) ? blockcnt[base + j] : 0;
        s += e[j];
    }
    sm[tid] = s;
    __syncthreads();
    for (int off = 1; off < 1024; off <<= 1) {
        int v = (tid >= off) ? sm[tid - off] : 0;
        __syncthreads();
        sm[tid] += v;
        __syncthreads();
    }
    int run = sm[tid] - s;
    #pragma unroll
    for (int j = 0; j < 20; ++j) {
        if (base + j < SCANA_N) {
            blockcnt[base + j] = run;
            run += e[j];
        }
    }
}

// scatter packed (dlocal<<17 | src) into bucket order — one store per edge
__global__ __launch_bounds__(256) void scatterA_kernel(const int* __restrict__ src,
                                                       const int* __restrict__ dst,
                                                       const int* __restrict__ blockcnt,
                                                       int* __restrict__ ebufP) {
    __shared__ int cur[NPART3];
    int tid = threadIdx.x;
    int b = blockIdx.x;
    if (tid < NPART3) cur[tid] = blockcnt[tid * NTB + b];
    __syncthreads();
    #pragma unroll
    for (int r = 0; r < 4; ++r) {
        int i4 = b * TILE4 + r * 256 + tid;
        if (i4 < NE / 4) {
            intx4 d = __builtin_nontemporal_load(&((const intx4*)dst)[i4]);
            intx4 s = __builtin_nontemporal_load(&((const intx4*)src)[i4]);
            int part, p;
            part = (unsigned)d.x / PSIZE3; p = atomicAdd(&cur[part], 1);
            ebufP[p] = ((d.x - part * PSIZE3) << SRCBITS) | s.x;
            part = (unsigned)d.y / PSIZE3; p = atomicAdd(&cur[part], 1);
            ebufP[p] = ((d.y - part * PSIZE3) << SRCBITS) | s.y;
            part = (unsigned)d.z / PSIZE3; p = atomicAdd(&cur[part], 1);
            ebufP[p] = ((d.z - part * PSIZE3) << SRCBITS) | s.z;
            part = (unsigned)d.w / PSIZE3; p = atomicAdd(&cur[part], 1);
            ebufP[p] = ((d.w - part * PSIZE3) << SRCBITS) | s.w;
        }
    }
}

// ---- one WG per partition: LDS hist -> in-WG scan -> row_start + csr ----
__global__ __launch_bounds__(1024) void fillD_kernel(const int* __restrict__ ebufP,
                                                     const int* __restrict__ blockcnt,
                                                     int* __restrict__ row_start,
                                                     int* __restrict__ csr) {
    __shared__ int cnt[PSIZE3];
    __shared__ int localstart[PSIZE3];
    __shared__ int partial[1024];
    int part = blockIdx.x;
    int tid = threadIdx.x;
    int nbase = part * PSIZE3;
    int base = blockcnt[part * NTB];
    int hi = (part < NPART3 - 1) ? blockcnt[(part + 1) * NTB] : NE;

    for (int j = tid; j < PSIZE3; j += 1024) cnt[j] = 0;
    __syncthreads();

    for (int i = base + tid; i < hi; i += 1024)
        atomicAdd(&cnt[(unsigned)ebufP[i] >> SRCBITS], 1);
    __syncthreads();

    int j0 = tid * 2;
    int e0 = (j0 < PSIZE3) ? cnt[j0] : 0;
    int e1 = (j0 + 1 < PSIZE3) ? cnt[j0 + 1] : 0;
    int s = e0 + e1;
    partial[tid] = s;
    __syncthreads();
    for (int off = 1; off < 1024; off <<= 1) {
        int v = (tid >= off) ? partial[tid - off] : 0;
        __syncthreads();
        partial[tid] += v;
        __syncthreads();
    }
    int run = partial[tid] - s;
    if (j0 < PSIZE3) localstart[j0] = run;
    if (j0 + 1 < PSIZE3) localstart[j0 + 1] = run + e0;
    __syncthreads();

    int nmax = NN - nbase; if (nmax > PSIZE3) nmax = PSIZE3;
    for (int j = tid; j < nmax; j += 1024)
        row_start[nbase + j] = base + localstart[j];
    if (part == NPART3 - 1 && tid == 0) row_start[NN] = NE;

    for (int j = tid; j < PSIZE3; j += 1024) cnt[j] = 0;
    __syncthreads();

    for (int i = base + tid; i < hi; i += 1024) {
        int p = ebufP[i];
        int dl = (unsigned)p >> SRCBITS;
        int local = atomicAdd(&cnt[dl], 1);
        csr[base + localstart[dl] + local] = p & ((1 << SRCBITS) - 1);
    }
}

// ---------------- FUSED per-layer: gather-max -> MFMA -> epilogue ----------------
// 64 nodes/block, 256 threads. Gather-max writes A cols 0..63 directly into the
// MFMA A-tile in LDS (no aggh round-trip); self rows staged into cols 64..127.
// hh is ping-ponged across layers (hin read-only, hout16 written) so fusion is
// race-free. fp32 out written only on last layer.
__global__ __launch_bounds__(256, 4) void fused_layer_kernel(
        const __half* __restrict__ hin,
        __half* __restrict__ hout16,
        float* __restrict__ houtf,
        const int* __restrict__ row_start,
        const int* __restrict__ csr,
        const float* __restrict__ Wl,
        const float* __restrict__ bl,
        const float* __restrict__ Wr,
        int last) {
    __shared__ char smem[2 * MB2 * APAD * 2];   // 34816 B, reused by epilogue
    _Float16* a_s  = (_Float16*)smem;                          // [64][APAD]
    _Float16* bt_s = (_Float16*)(smem + MB2 * APAD * 2);       // [64][APAD], n-major

    int tid = threadIdx.x;
    int lane = tid & 63;
    int w = tid >> 6;
    int node0 = blockIdx.x * MB2;

    // stage Bt[n][k] = (fp16) W[k][n], W = [Wl ; Wr]
    {
        int n = tid & 63;
        int kb = tid >> 6;
        #pragma unroll
        for (int kk = 0; kk < 32; ++kk) {
            int k = kb * 32 + kk;
            float wv = (k < 64) ? Wl[k * DD + n] : Wr[(k - 64) * DD + n];
            bt_s[n * APAD + k] = (_Float16)wv;
        }
    }
    // stage self rows into a_s cols 64..127
    #pragma unroll
    for (int i = 0; i < 2; ++i) {
        int idx = i * 256 + tid;          // 512 uint4s
        int r = idx >> 3;
        int c = idx & 7;
        int node = node0 + r; if (node > NN - 1) node = NN - 1;
        *(uint4*)&a_s[r * APAD + DD + c * 8] =
            *(const uint4*)&hin[(size_t)node * DD + c * 8];
    }

    // gather-max into a_s cols 0..63; wave w handles rows w*16 .. w*16+15
    int g = lane >> 3;              // neighbor sub-slot 0..7
    int c8 = (lane & 7) * 8;        // column base (halfs)
    for (int i = 0; i < 16; ++i) {
        int r = w * 16 + i;
        int n = node0 + r; if (n > NN - 1) n = NN - 1;
        int base = row_start[n];
        int cnt = row_start[n + 1] - base;
        uint4 acc = make_uint4(0, 0, 0, 0);      // PyG empty-segment -> 0
        if (cnt > 0) {
            int clampi = cnt - 1;
            int pre = (lane <= clampi) ? lane : clampi;
            int idx = csr[base + pre];           // coalesced 256B index preload
            acc = make_uint4(0xFC00FC00u, 0xFC00FC00u, 0xFC00FC00u, 0xFC00FC00u);
            int kmax = (cnt < 64) ? cnt : 64;
            for (int k = 0; k < kmax; k += 16) {
                int k0 = k + g;
                int k1 = k + g + 8;
                int s0 = __shfl(idx, (k0 <= clampi) ? k0 : clampi, 64);
                int s1 = __shfl(idx, (k1 <= clampi) ? k1 : clampi, 64);
                if (k0 < cnt) {
                    uint4 u0 = *(const uint4*)&hin[(size_t)s0 * DD + c8];
                    acc.x = umax2(acc.x, u0.x);
                    acc.y = umax2(acc.y, u0.y);
                    acc.z = umax2(acc.z, u0.z);
                    acc.w = umax2(acc.w, u0.w);
                }
                if (k1 < cnt) {
                    uint4 u1 = *(const uint4*)&hin[(size_t)s1 * DD + c8];
                    acc.x = umax2(acc.x, u1.x);
                    acc.y = umax2(acc.y, u1.y);
                    acc.z = umax2(acc.z, u1.z);
                    acc.w = umax2(acc.w, u1.w);
                }
            }
            for (int k = 64 + g; k < cnt; k += 8) {   // ultra-rare tail
                int s = csr[base + k];
                uint4 u = *(const uint4*)&hin[(size_t)s * DD + c8];
                acc.x = umax2(acc.x, u.x);
                acc.y = umax2(acc.y, u.y);
                acc.z = umax2(acc.z, u.z);
                acc.w = umax2(acc.w, u.w);
            }
            #pragma unroll
            for (int off = 8; off <= 32; off <<= 1) {
                acc.x = umax2(acc.x, (unsigned)__shfl_xor((int)acc.x, off, 64));
                acc.y = umax2(acc.y, (unsigned)__shfl_xor((int)acc.y, off, 64));
                acc.z = umax2(acc.z, (unsigned)__shfl_xor((int)acc.z, off, 64));
                acc.w = umax2(acc.w, (unsigned)__shfl_xor((int)acc.w, off, 64));
            }
        }
        if (lane < 8) *(uint4*)&a_s[r * APAD + c8] = acc;
    }
    __syncthreads();

    // MFMA: wave strip 16 nodes x 64 cols, mfma_f32_16x16x32_f16
    floatx4 acc[4];
    #pragma unroll
    for (int nt = 0; nt < 4; ++nt) acc[nt] = (floatx4){0.f, 0.f, 0.f, 0.f};
    int m = lane & 15;
    int q = lane >> 4;

    #pragma unroll
    for (int ks = 0; ks < 4; ++ks) {
        half8 af = *(half8*)&a_s[(w * 16 + m) * APAD + q * 8 + ks * 32];
        #pragma unroll
        for (int nt = 0; nt < 4; ++nt) {
            half8 bf = *(half8*)&bt_s[(nt * 16 + m) * APAD + q * 8 + ks * 32];
            acc[nt] = __builtin_amdgcn_mfma_f32_16x16x32_f16(af, bf, acc[nt], 0, 0, 0);
        }
    }
    __syncthreads();    // done with a_s/bt_s; reuse smem for epilogue

    _Float16* ch = (_Float16*)smem;                      // [64][CPADH]
    float*    cf = (float*)(smem + MB2 * CPADH * 2);     // [64][CPADF]

    #pragma unroll
    for (int nt = 0; nt < 4; ++nt) {
        int col = nt * 16 + m;
        float b = bl[col];
        #pragma unroll
        for (int r = 0; r < 4; ++r) {
            int rowl = w * 16 + q * 4 + r;
            float o = fmaxf(acc[nt][r] + b, 0.0f);
            ch[rowl * CPADH + col] = (_Float16)o;
            if (last) cf[rowl * CPADF + col] = o;
        }
    }
    __syncthreads();

    #pragma unroll
    for (int i = 0; i < 2; ++i) {
        int idx = i * 256 + tid;          // 512 uint4s
        int r = idx >> 3;
        int c4 = idx & 7;
        int node = node0 + r;
        if (node < NN) {
            uint4 v = *(uint4*)&ch[r * CPADH + c4 * 8];
            *(uint4*)&hout16[(size_t)node * DD + c4 * 8] = v;
        }
    }
    if (last) {
        #pragma unroll
        for (int i = 0; i < 4; ++i) {
            int idx = i * 256 + tid;      // 1024 float4s
            int r = idx >> 4;
            int c4 = idx & 15;
            int node = node0 + r;
            if (node < NN) {
                float4 v = *(float4*)&cf[r * CPADF + c4 * 4];
                *(float4*)&houtf[(size_t)node * DD + c4 * 4] = v;
            }
        }
    }
}

extern "C" void kernel_launch(void* const* d_in, const int* in_sizes, int n_in,
                              void* d_out, int out_size, void* d_ws, size_t ws_size,
                              hipStream_t stream) {
    const float* x  = (const float*)d_in[0];
    const int*   ei = (const int*)d_in[1];
    const float* Wl = (const float*)d_in[2];
    const float* bl = (const float*)d_in[3];
    const float* Wr = (const float*)d_in[4];
    float* h = (float*)d_out;

    const int* src = ei;
    const int* dst = ei + NE;

    char* ws = (char*)d_ws;
    __half* hh0      = (__half*)ws;  ws += (size_t)NN * DD * sizeof(__half);  // 12.8 MB
    __half* hh1      = (__half*)ws;  ws += (size_t)NN * DD * sizeof(__half);  // 12.8 MB
    int* row_start   = (int*)ws;     ws += (size_t)(NN + 16) * sizeof(int);
    int* blockcnt    = (int*)ws;     ws += (size_t)(SCANA_N + 16) * sizeof(int);
    int* csr         = (int*)ws;                                              // 5 MB

    // packed edge bucket overlays hh1 (dead until fused layer 0 writes it,
    // which happens after fillD has consumed ebufP)
    int* ebufP = (int*)hh1;                      // NE ints = 5 MB <= 12.8 MB

    cast_kernel<<<(NN * DD / 4) / 256, 256, 0, stream>>>(x, hh0);

    countA_kernel<<<NTB, 256, 0, stream>>>(dst, blockcnt);
    scanA_kernel<<<1, 1024, 0, stream>>>(blockcnt);
    scatterA_kernel<<<NTB, 256, 0, stream>>>(src, dst, blockcnt, ebufP);
    fillD_kernel<<<NPART3, 1024, 0, stream>>>(ebufP, blockcnt, row_start, csr);

    for (int l = 0; l < NL; ++l) {
        const __half* hin = (l & 1) ? hh1 : hh0;
        __half* hout16    = (l & 1) ? hh0 : hh1;
        fused_layer_kernel<<<L2BLOCKS, 256, 0, stream>>>(
            hin, hout16, h, row_start, csr,
            Wl + (size_t)l * DD * DD, bl + (size_t)l * DD, Wr + (size_t)l * DD * DD,
            (l == NL - 1) ? 1 : 0);
    }
}

// Round 15
// 303.897 us; speedup vs baseline: 1.2694x; 1.2694x over previous
//
#include <hip/hip_runtime.h>
#include <hip/hip_fp16.h>
#include <stdint.h>

#define NN 100000
#define NE 1250000
#define DD 64
#define NL 4

#define NPART3 64            // partitions; one WG owns one partition in fillD
#define PSIZE3 1563          // nodes per partition (64*1563 = 100032 >= NN)
#define TILE4 1024           // int4s per radix tile = 4096 edges
#define NTB ((NE / 4 + TILE4 - 1) / TILE4)        // 306 tiles
#define SCANA_N (NPART3 * NTB)                    // 19584
#define SRCBITS 17           // src < 100000 < 2^17; dlocal < 1563 < 2^11

#define MB2 64               // nodes per MFMA layer block
#define L2BLOCKS ((NN + MB2 - 1) / MB2)   // 1563
#define APAD 136             // halfs per A/Bt LDS row
#define CPADH 72             // halfs per C row
#define CPADF 68             // floats per C row

typedef _Float16 half8 __attribute__((ext_vector_type(8)));
typedef _Float16 half2v __attribute__((ext_vector_type(2)));
typedef float floatx4 __attribute__((ext_vector_type(4)));
typedef int intx4 __attribute__((ext_vector_type(4)));

__device__ __forceinline__ unsigned f2h2(float a, float b) {
    __half2 h = __floats2half2_rn(a, b);
    return *reinterpret_cast<unsigned*>(&h);
}
// packed fp16 max on raw bits (maps to v_pk_max_f16)
__device__ __forceinline__ unsigned umax2(unsigned a, unsigned b) {
    half2v x = *reinterpret_cast<half2v*>(&a);
    half2v y = *reinterpret_cast<half2v*>(&b);
    half2v r = __builtin_elementwise_max(x, y);
    return *reinterpret_cast<unsigned*>(&r);
}

// ---- x (fp32) -> hh (fp16) ----
__global__ __launch_bounds__(256) void cast_kernel(const float* __restrict__ x,
                                                   __half* __restrict__ hh) {
    int i = blockIdx.x * 256 + threadIdx.x;
    float4 v = ((const float4*)x)[i];
    uint2 u;
    u.x = f2h2(v.x, v.y);
    u.y = f2h2(v.z, v.w);
    ((uint2*)hh)[i] = u;
}

// ---------------- radix bucketing: edges -> 64 dst-partition buckets ----------------
__global__ __launch_bounds__(256) void countA_kernel(const int* __restrict__ dst,
                                                     int* __restrict__ blockcnt) {
    __shared__ int cnt[NPART3];
    int tid = threadIdx.x;
    if (tid < NPART3) cnt[tid] = 0;
    __syncthreads();
    int b = blockIdx.x;
    #pragma unroll
    for (int r = 0; r < 4; ++r) {
        int i4 = b * TILE4 + r * 256 + tid;
        if (i4 < NE / 4) {
            intx4 d = __builtin_nontemporal_load(&((const intx4*)dst)[i4]);
            atomicAdd(&cnt[(unsigned)d.x / PSIZE3], 1);
            atomicAdd(&cnt[(unsigned)d.y / PSIZE3], 1);
            atomicAdd(&cnt[(unsigned)d.z / PSIZE3], 1);
            atomicAdd(&cnt[(unsigned)d.w / PSIZE3], 1);
        }
    }
    __syncthreads();
    if (tid < NPART3) blockcnt[tid * NTB + b] = cnt[tid];
}

// exclusive scan over NPART3*NTB = 19584 counts (bucket-major -> global offsets)
__global__ __launch_bounds__(1024) void scanA_kernel(int* __restrict__ blockcnt) {
    __shared__ int sm[1024];
    int tid = threadIdx.x;
    int base = tid * 20;
    int e[20];
    int s = 0;
    #pragma unroll
    for (int j = 0; j < 20; ++j) {
        e[j] = (base + j < SCANA_N) ? blockcnt[base + j] : 0;
        s += e[j];
    }
    sm[tid] = s;
    __syncthreads();
    for (int off = 1; off < 1024; off <<= 1) {
        int v = (tid >= off) ? sm[tid - off] : 0;
        __syncthreads();
        sm[tid] += v;
        __syncthreads();
    }
    int run = sm[tid] - s;
    #pragma unroll
    for (int j = 0; j < 20; ++j) {
        if (base + j < SCANA_N) {
            blockcnt[base + j] = run;
            run += e[j];
        }
    }
}

// scatter packed (dlocal<<17 | src) into bucket order — one store per edge
__global__ __launch_bounds__(256) void scatterA_kernel(const int* __restrict__ src,
                                                       const int* __restrict__ dst,
                                                       const int* __restrict__ blockcnt,
                                                       int* __restrict__ ebufP) {
    __shared__ int cur[NPART3];
    int tid = threadIdx.x;
    int b = blockIdx.x;
    if (tid < NPART3) cur[tid] = blockcnt[tid * NTB + b];
    __syncthreads();
    #pragma unroll
    for (int r = 0; r < 4; ++r) {
        int i4 = b * TILE4 + r * 256 + tid;
        if (i4 < NE / 4) {
            intx4 d = __builtin_nontemporal_load(&((const intx4*)dst)[i4]);
            intx4 s = __builtin_nontemporal_load(&((const intx4*)src)[i4]);
            int part, p;
            part = (unsigned)d.x / PSIZE3; p = atomicAdd(&cur[part], 1);
            ebufP[p] = ((d.x - part * PSIZE3) << SRCBITS) | s.x;
            part = (unsigned)d.y / PSIZE3; p = atomicAdd(&cur[part], 1);
            ebufP[p] = ((d.y - part * PSIZE3) << SRCBITS) | s.y;
            part = (unsigned)d.z / PSIZE3; p = atomicAdd(&cur[part], 1);
            ebufP[p] = ((d.z - part * PSIZE3) << SRCBITS) | s.z;
            part = (unsigned)d.w / PSIZE3; p = atomicAdd(&cur[part], 1);
            ebufP[p] = ((d.w - part * PSIZE3) << SRCBITS) | s.w;
        }
    }
}

// ---- one WG per partition: LDS hist -> in-WG scan -> row_start + csr ----
__global__ __launch_bounds__(1024) void fillD_kernel(const int* __restrict__ ebufP,
                                                     const int* __restrict__ blockcnt,
                                                     int* __restrict__ row_start,
                                                     int* __restrict__ csr) {
    __shared__ int cnt[PSIZE3];
    __shared__ int localstart[PSIZE3];
    __shared__ int partial[1024];
    int part = blockIdx.x;
    int tid = threadIdx.x;
    int nbase = part * PSIZE3;
    int base = blockcnt[part * NTB];
    int hi = (part < NPART3 - 1) ? blockcnt[(part + 1) * NTB] : NE;

    for (int j = tid; j < PSIZE3; j += 1024) cnt[j] = 0;
    __syncthreads();

    for (int i = base + tid; i < hi; i += 1024)
        atomicAdd(&cnt[(unsigned)ebufP[i] >> SRCBITS], 1);
    __syncthreads();

    int j0 = tid * 2;
    int e0 = (j0 < PSIZE3) ? cnt[j0] : 0;
    int e1 = (j0 + 1 < PSIZE3) ? cnt[j0 + 1] : 0;
    int s = e0 + e1;
    partial[tid] = s;
    __syncthreads();
    for (int off = 1; off < 1024; off <<= 1) {
        int v = (tid >= off) ? partial[tid - off] : 0;
        __syncthreads();
        partial[tid] += v;
        __syncthreads();
    }
    int run = partial[tid] - s;
    if (j0 < PSIZE3) localstart[j0] = run;
    if (j0 + 1 < PSIZE3) localstart[j0 + 1] = run + e0;
    __syncthreads();

    int nmax = NN - nbase; if (nmax > PSIZE3) nmax = PSIZE3;
    for (int j = tid; j < nmax; j += 1024)
        row_start[nbase + j] = base + localstart[j];
    if (part == NPART3 - 1 && tid == 0) row_start[NN] = NE;

    for (int j = tid; j < PSIZE3; j += 1024) cnt[j] = 0;
    __syncthreads();

    for (int i = base + tid; i < hi; i += 1024) {
        int p = ebufP[i];
        int dl = (unsigned)p >> SRCBITS;
        int local = atomicAdd(&cnt[dl], 1);
        csr[base + localstart[dl] + local] = p & ((1 << SRCBITS) - 1);
    }
}

// ---------------- per-layer gather-max: TWO nodes per wave ----------------
// Doubles outstanding loads per wave (latency x concurrency bound regime):
// 2 csr preloads + up to 4 row loads in flight per iteration. cnt0/cnt1 are
// wave-uniform so all branches are wave-uniform.
__global__ __launch_bounds__(256) void agg_kernel(const __half* __restrict__ hh,
                                                  const int* __restrict__ row_start,
                                                  const int* __restrict__ csr,
                                                  __half* __restrict__ aggh) {
    int tid = threadIdx.x;
    int wv = tid >> 6;
    int lane = tid & 63;
    int g = lane >> 3;              // neighbor sub-slot 0..7
    int c8 = (lane & 7) * 8;        // column base (halfs)
    int n0 = blockIdx.x * 8 + wv * 2;   // NN = 12500*8 exactly
    int n1 = n0 + 1;
    int base0 = row_start[n0];
    int base1 = row_start[n1];
    int cnt0 = base1 - base0;
    int cnt1 = row_start[n1 + 1] - base1;
    int cl0 = cnt0 - 1;
    int cl1 = cnt1 - 1;

    // coalesced index preloads for both nodes (independent, in flight together)
    int idx0 = 0, idx1 = 0;
    if (cnt0 > 0) idx0 = csr[base0 + ((lane <= cl0) ? lane : cl0)];
    if (cnt1 > 0) idx1 = csr[base1 + ((lane <= cl1) ? lane : cl1)];

    const uint4 NI4 = make_uint4(0xFC00FC00u, 0xFC00FC00u, 0xFC00FC00u, 0xFC00FC00u);
    uint4 acc0 = (cnt0 > 0) ? NI4 : make_uint4(0, 0, 0, 0);
    uint4 acc1 = (cnt1 > 0) ? NI4 : make_uint4(0, 0, 0, 0);

    int m0 = (cnt0 < 64) ? cnt0 : 64;
    int m1 = (cnt1 < 64) ? cnt1 : 64;
    int kmax = (m0 > m1) ? m0 : m1;

    for (int k = 0; k < kmax; k += 16) {
        int ka = k + g;
        int kb = k + g + 8;
        int s00 = 0, s01 = 0, s10 = 0, s11 = 0;
        if (cnt0 > 0) {
            s00 = __shfl(idx0, (ka <= cl0) ? ka : cl0, 64);
            s01 = __shfl(idx0, (kb <= cl0) ? kb : cl0, 64);
        }
        if (cnt1 > 0) {
            s10 = __shfl(idx1, (ka <= cl1) ? ka : cl1, 64);
            s11 = __shfl(idx1, (kb <= cl1) ? kb : cl1, 64);
        }
        // issue all in-range loads back-to-back (4 independent requests)
        if (ka < m0) {
            uint4 u = *(const uint4*)&hh[(size_t)s00 * DD + c8];
            acc0.x = umax2(acc0.x, u.x); acc0.y = umax2(acc0.y, u.y);
            acc0.z = umax2(acc0.z, u.z); acc0.w = umax2(acc0.w, u.w);
        }
        if (ka < m1) {
            uint4 u = *(const uint4*)&hh[(size_t)s10 * DD + c8];
            acc1.x = umax2(acc1.x, u.x); acc1.y = umax2(acc1.y, u.y);
            acc1.z = umax2(acc1.z, u.z); acc1.w = umax2(acc1.w, u.w);
        }
        if (kb < m0) {
            uint4 u = *(const uint4*)&hh[(size_t)s01 * DD + c8];
            acc0.x = umax2(acc0.x, u.x); acc0.y = umax2(acc0.y, u.y);
            acc0.z = umax2(acc0.z, u.z); acc0.w = umax2(acc0.w, u.w);
        }
        if (kb < m1) {
            uint4 u = *(const uint4*)&hh[(size_t)s11 * DD + c8];
            acc1.x = umax2(acc1.x, u.x); acc1.y = umax2(acc1.y, u.y);
            acc1.z = umax2(acc1.z, u.z); acc1.w = umax2(acc1.w, u.w);
        }
    }
    // ultra-rare tails (cnt > 64)
    for (int k = 64 + g; k < cnt0; k += 8) {
        int s = csr[base0 + k];
        uint4 u = *(const uint4*)&hh[(size_t)s * DD + c8];
        acc0.x = umax2(acc0.x, u.x); acc0.y = umax2(acc0.y, u.y);
        acc0.z = umax2(acc0.z, u.z); acc0.w = umax2(acc0.w, u.w);
    }
    for (int k = 64 + g; k < cnt1; k += 8) {
        int s = csr[base1 + k];
        uint4 u = *(const uint4*)&hh[(size_t)s * DD + c8];
        acc1.x = umax2(acc1.x, u.x); acc1.y = umax2(acc1.y, u.y);
        acc1.z = umax2(acc1.z, u.z); acc1.w = umax2(acc1.w, u.w);
    }

    // cross-group reduce (xor 8/16/32) in packed half2, both nodes
    #pragma unroll
    for (int off = 8; off <= 32; off <<= 1) {
        acc0.x = umax2(acc0.x, (unsigned)__shfl_xor((int)acc0.x, off, 64));
        acc0.y = umax2(acc0.y, (unsigned)__shfl_xor((int)acc0.y, off, 64));
        acc0.z = umax2(acc0.z, (unsigned)__shfl_xor((int)acc0.z, off, 64));
        acc0.w = umax2(acc0.w, (unsigned)__shfl_xor((int)acc0.w, off, 64));
        acc1.x = umax2(acc1.x, (unsigned)__shfl_xor((int)acc1.x, off, 64));
        acc1.y = umax2(acc1.y, (unsigned)__shfl_xor((int)acc1.y, off, 64));
        acc1.z = umax2(acc1.z, (unsigned)__shfl_xor((int)acc1.z, off, 64));
        acc1.w = umax2(acc1.w, (unsigned)__shfl_xor((int)acc1.w, off, 64));
    }
    if (lane < 8) {
        *(uint4*)&aggh[(size_t)n0 * DD + c8] = acc0;
        *(uint4*)&aggh[(size_t)n1 * DD + c8] = acc1;
    }
}

// ---------------- dense update via MFMA ----------------
__global__ __launch_bounds__(256, 4) void layer_mfma_kernel(
        const __half* __restrict__ aggh,
        __half* __restrict__ hh,
        float* __restrict__ hout,
        const float* __restrict__ Wl,
        const float* __restrict__ bl,
        const float* __restrict__ Wr,
        int last) {
    __shared__ char smem[2 * MB2 * APAD * 2];   // 34816 B, reused by epilogue
    _Float16* a_s  = (_Float16*)smem;                          // [64][APAD]
    _Float16* bt_s = (_Float16*)(smem + MB2 * APAD * 2);       // [64][APAD], n-major

    int tid = threadIdx.x;
    int lane = tid & 63;
    int w = tid >> 6;
    int node0 = blockIdx.x * MB2;

    #pragma unroll
    for (int i = 0; i < 4; ++i) {
        int idx = i * 256 + tid;          // uint4 id, 1024 total
        int r = idx >> 4;
        int c4 = idx & 15;
        int node = node0 + r; if (node > NN - 1) node = NN - 1;
        const __half* srcp = (c4 < 8) ? (aggh + (size_t)node * DD + c4 * 8)
                                      : (hh + (size_t)node * DD + (c4 - 8) * 8);
        uint4 v = *(const uint4*)srcp;
        *(uint4*)&a_s[r * APAD + c4 * 8] = v;
    }
    {
        int n = tid & 63;
        int kb = tid >> 6;
        #pragma unroll
        for (int kk = 0; kk < 32; ++kk) {
            int k = kb * 32 + kk;
            float wv = (k < 64) ? Wl[k * DD + n] : Wr[(k - 64) * DD + n];
            bt_s[n * APAD + k] = (_Float16)wv;
        }
    }
    __syncthreads();

    floatx4 acc[4];
    #pragma unroll
    for (int nt = 0; nt < 4; ++nt) acc[nt] = (floatx4){0.f, 0.f, 0.f, 0.f};
    int m = lane & 15;
    int q = lane >> 4;

    #pragma unroll
    for (int ks = 0; ks < 4; ++ks) {
        half8 af = *(half8*)&a_s[(w * 16 + m) * APAD + q * 8 + ks * 32];
        #pragma unroll
        for (int nt = 0; nt < 4; ++nt) {
            half8 bf = *(half8*)&bt_s[(nt * 16 + m) * APAD + q * 8 + ks * 32];
            acc[nt] = __builtin_amdgcn_mfma_f32_16x16x32_f16(af, bf, acc[nt], 0, 0, 0);
        }
    }
    __syncthreads();

    _Float16* ch = (_Float16*)smem;                      // [64][CPADH]
    float*    cf = (float*)(smem + MB2 * CPADH * 2);     // [64][CPADF]

    #pragma unroll
    for (int nt = 0; nt < 4; ++nt) {
        int col = nt * 16 + m;
        float b = bl[col];
        #pragma unroll
        for (int r = 0; r < 4; ++r) {
            int rowl = w * 16 + q * 4 + r;
            float o = fmaxf(acc[nt][r] + b, 0.0f);
            ch[rowl * CPADH + col] = (_Float16)o;
            if (last) cf[rowl * CPADF + col] = o;
        }
    }
    __syncthreads();

    #pragma unroll
    for (int i = 0; i < 2; ++i) {
        int idx = i * 256 + tid;          // 512 uint4s
        int r = idx >> 3;
        int c4 = idx & 7;
        int node = node0 + r;
        if (node < NN) {
            uint4 v = *(uint4*)&ch[r * CPADH + c4 * 8];
            *(uint4*)&hh[(size_t)node * DD + c4 * 8] = v;
        }
    }
    if (last) {
        #pragma unroll
        for (int i = 0; i < 4; ++i) {
            int idx = i * 256 + tid;      // 1024 float4s
            int r = idx >> 4;
            int c4 = idx & 15;
            int node = node0 + r;
            if (node < NN) {
                float4 v = *(float4*)&cf[r * CPADF + c4 * 4];
                *(float4*)&hout[(size_t)node * DD + c4 * 4] = v;
            }
        }
    }
}

extern "C" void kernel_launch(void* const* d_in, const int* in_sizes, int n_in,
                              void* d_out, int out_size, void* d_ws, size_t ws_size,
                              hipStream_t stream) {
    const float* x  = (const float*)d_in[0];
    const int*   ei = (const int*)d_in[1];
    const float* Wl = (const float*)d_in[2];
    const float* bl = (const float*)d_in[3];
    const float* Wr = (const float*)d_in[4];
    float* h = (float*)d_out;

    const int* src = ei;
    const int* dst = ei + NE;

    char* ws = (char*)d_ws;
    __half* aggh     = (__half*)ws;  ws += (size_t)NN * DD * sizeof(__half);  // 12.8 MB
    __half* hh       = (__half*)ws;  ws += (size_t)NN * DD * sizeof(__half);  // 12.8 MB
    int* row_start   = (int*)ws;     ws += (size_t)(NN + 16) * sizeof(int);
    int* blockcnt    = (int*)ws;     ws += (size_t)(SCANA_N + 16) * sizeof(int);
    int* csr         = (int*)ws;                                              // 5 MB

    // packed edge bucket reuses the aggh region (dead until first agg_kernel)
    int* ebufP = (int*)aggh;                     // NE ints = 5 MB <= 12.8 MB

    cast_kernel<<<(NN * DD / 4) / 256, 256, 0, stream>>>(x, hh);

    countA_kernel<<<NTB, 256, 0, stream>>>(dst, blockcnt);
    scanA_kernel<<<1, 1024, 0, stream>>>(blockcnt);
    scatterA_kernel<<<NTB, 256, 0, stream>>>(src, dst, blockcnt, ebufP);
    fillD_kernel<<<NPART3, 1024, 0, stream>>>(ebufP, blockcnt, row_start, csr);

    for (int l = 0; l < NL; ++l) {
        agg_kernel<<<NN / 8, 256, 0, stream>>>(hh, row_start, csr, aggh);
        layer_mfma_kernel<<<L2BLOCKS, 256, 0, stream>>>(
            aggh, hh, h, Wl + (size_t)l * DD * DD, bl + (size_t)l * DD, Wr + (size_t)l * DD * DD,
            (l == NL - 1) ? 1 : 0);
    }
}